// Round 6
// baseline (315.173 us; speedup 1.0000x reference)
//
#include <hip/hip_runtime.h>

// VQ-VAE quantization. x: [32,64,64,64] fp32, emb: [1024,64] fp32
#define BATCH   32
#define CCH     64
#define HW      4096
#define NPIX    (BATCH * HW)        // 131072
#define KCODES  1024
#define NELEM   (NPIX * CCH)        // 8388608
#define MB      256                 // pixels per block (64 per wave, 4 row-tiles)
#define CK      64                  // codes per LDS chunk
#define KSPLIT  2                   // codebook halves across blocks
#define MARGIN_Q 2u                 // ambiguity margin, 1/2048 distance units

typedef _Float16 f16;
typedef __attribute__((ext_vector_type(8))) _Float16 f16x8;
typedef __attribute__((ext_vector_type(4))) float    f32x4;

static __device__ __forceinline__ f32x4 mfma16(f16x8 a, f16x8 b, f32x4 c) {
    return __builtin_amdgcn_mfma_f32_16x16x32_f16(a, b, c, 0, 0, 0);
}

static __device__ __forceinline__ void dma16(void* lds, const void* g) {
    __builtin_amdgcn_global_load_lds(
        (const __attribute__((address_space(1))) unsigned int*)g,
        (__attribute__((address_space(3))) unsigned int*)lds, 16, 0, 0);
}

// ws layout (bytes):
//   [0] f32 loss acc   [4] u32 worklist count
//   [256..4352)        eeb[k] = 2048*||e_k||^2 + 2^20  (1024 f32)
//   [8192..139264)     cbH swizzled fp16-hi codebook
//   [139264..270336)   cbL fp16-lo, same swizzle
//   [270336..1318912)  pb_best [half][n]  u32
//   [1318912..2367488) pb_best2 [half][n] u32
//   [2367488..)        worklist (u32)
#define WS_EEB_F   64
#define WS_CBH_B   8192
#define WS_CBL_B   139264
#define WS_PB1_U   67584
#define WS_PB2_U   329728
#define WS_WL_U    591872

__global__ __launch_bounds__(256) void vq_prep(
    const float* __restrict__ emb, float* __restrict__ wsf,
    unsigned* __restrict__ wsu, f16* __restrict__ cbH, f16* __restrict__ cbL,
    float* __restrict__ eeb_g)
{
    const int t = threadIdx.x;
    if (blockIdx.x < 32) {
        const int gid = blockIdx.x * 256 + t;        // 0..8191 granules
        const int row = gid >> 3, gi = gid & 7;
        const float* src = emb + (size_t)row * CCH + gi * 8;
        float4 v0 = *(const float4*)(src);
        float4 v1 = *(const float4*)(src + 4);
        float vv[8] = {v0.x, v0.y, v0.z, v0.w, v1.x, v1.y, v1.z, v1.w};
        f16x8 h, l;
#pragma unroll
        for (int j = 0; j < 8; ++j) {
            f16 hh = (f16)vv[j];
            h[j] = hh;
            l[j] = (f16)(vv[j] - (float)hh);
        }
        const int off = row * 64 + 8 * (gi ^ (row & 7));
        *(f16x8*)(cbH + off) = h;
        *(f16x8*)(cbL + off) = l;
    } else {
        if (t == 0) { wsf[0] = 0.f; wsu[1] = 0u; }
        for (int r = t * 4; r < t * 4 + 4; ++r) {
            const float4* row4 = (const float4*)(emb + (size_t)r * CCH);
            float s = 0.f;
#pragma unroll
            for (int i = 0; i < 16; ++i) {
                float4 v = row4[i];
                s = fmaf(v.x, v.x, s); s = fmaf(v.y, v.y, s);
                s = fmaf(v.z, v.z, s); s = fmaf(v.w, v.w, s);
            }
            eeb_g[r] = fmaf(s, 2048.0f, 1048576.0f);
        }
    }
}

__global__ __launch_bounds__(256, 4) void vq_main(
    const float* __restrict__ x,
    const f16* __restrict__ cbH, const f16* __restrict__ cbL,
    const float* __restrict__ eeb_g,
    unsigned* __restrict__ pb1, unsigned* __restrict__ pb2)
{
    __shared__ __align__(16) char smem[32768];      // 2 x (8K H | 8K L)
    __shared__ float eebl[2][CK];
    __shared__ unsigned bu1[MB], bu2[MB];

    const int t    = threadIdx.x;
    const int lane = t & 63;
    const int w    = t >> 6;
    const int col  = lane & 15;
    const int quad = lane >> 4;
    const int c7   = col & 7;
    const int sw0  = 8 * (quad ^ c7);
    const int sw1  = sw0 ^ 32;
    const int half = blockIdx.x & 1;                // codebook half
    const int gb   = blockIdx.x >> 1;               // pixel group
    const int n0   = gb * MB;
    const int b    = n0 >> 12;
    const int p0   = n0 & 4095;
    const int ch0  = half * (KCODES / CK / KSPLIT); // first chunk (8 per half)
    const float* xb = x + (size_t)b * (CCH * HW) + p0;

    auto stage = [&](int chunkAbs, int bufi) {
        const int k0 = chunkAbs * CK;
        char* lb = smem + bufi * 16384;
        const char* gH = (const char*)cbH + (size_t)k0 * 128 + w * 2048 + lane * 16;
        const char* gL = (const char*)cbL + (size_t)k0 * 128 + w * 2048 + lane * 16;
        char* lH = lb + w * 2048;
        char* lL = lb + 8192 + w * 2048;
        dma16(lH,        gH);
        dma16(lH + 1024, gH + 1024);
        dma16(lL,        gL);
        dma16(lL + 1024, gL + 1024);
        if (t < CK) eebl[bufi][t] = eeb_g[k0 + t];
    };

    stage(ch0, 0);     // DMA in flight while we build A fragments

    // ---- A fragments straight from global (MFMA A-layout) ----
    f16x8 aH[4][2], aL[4][2];
#pragma unroll
    for (int rt = 0; rt < 4; ++rt) {
        const int pp = w * 64 + rt * 16 + col;
#pragma unroll
        for (int kc = 0; kc < 2; ++kc) {
            f16x8 h, l;
#pragma unroll
            for (int j = 0; j < 8; ++j) {
                const int c = kc * 32 + quad * 8 + j;
                float zs = -2.0f * xb[(size_t)c * HW + pp];
                f16 hh = (f16)zs;
                h[j] = hh;
                l[j] = (f16)(zs - (float)hh);
            }
            aH[rt][kc] = h;
            aL[rt][kc] = l;
        }
    }

    unsigned best[16], best2[16];
#pragma unroll
    for (int s = 0; s < 16; ++s) { best[s] = 0xFFFFFFFFu; best2[s] = 0xFFFFFFFFu; }

    const int NCH = KCODES / CK / KSPLIT;           // 8 chunks per block
    for (int chunk = 0; chunk < NCH; ++chunk) {
        const int cur = chunk & 1;
        __syncthreads();                            // chunk's DMA visible
        if (chunk + 1 < NCH) stage(ch0 + chunk + 1, cur ^ 1);

        const f16* bufH = (const f16*)(smem + cur * 16384);
        const f16* bufL = bufH + 4096;
        const int k0 = (ch0 + chunk) * CK;

#pragma unroll
        for (int tile = 0; tile < CK / 16; ++tile) {
            const f16* bh = bufH + (tile * 16 + col) * 64;
            const f16* bl = bufL + (tile * 16 + col) * 64;
            f16x8 bH0 = *(const f16x8*)(bh + sw0);
            f16x8 bH1 = *(const f16x8*)(bh + sw1);
            f16x8 bL0 = *(const f16x8*)(bl + sw0);
            f16x8 bL1 = *(const f16x8*)(bl + sw1);
            const float eebc = eebl[cur][tile * 16 + col];
            const unsigned kb = (unsigned)(k0 + tile * 16 + col);
#pragma unroll
            for (int rt = 0; rt < 4; ++rt) {
                f32x4 a4 = {0.f, 0.f, 0.f, 0.f};
                a4 = mfma16(aH[rt][0], bH0, a4);
                a4 = mfma16(aH[rt][1], bH1, a4);
                a4 = mfma16(aL[rt][0], bH0, a4);
                a4 = mfma16(aL[rt][1], bH1, a4);
                a4 = mfma16(aH[rt][0], bL0, a4);
                a4 = mfma16(aH[rt][1], bL1, a4);
#pragma unroll
                for (int r = 0; r < 4; ++r) {
                    float uf = fmaf(a4[r], 2048.0f, eebc);   // in (0, 2^21)
                    unsigned pk = (((unsigned)uf) << 10) | kb;
                    const int s = rt * 4 + r;
                    best2[s] = min(best2[s], max(pk, best[s]));
                    best[s]  = min(best[s], pk);
                }
            }
        }
    }

    // ---- cross-lane argmin reduce over the 16 code-columns ----
#pragma unroll
    for (int d = 1; d < 16; d <<= 1) {
#pragma unroll
        for (int s = 0; s < 16; ++s) {
            unsigned ob  = __shfl_xor(best[s],  d, 64);
            unsigned ob2 = __shfl_xor(best2[s], d, 64);
            best2[s] = min(min(best2[s], ob2), max(best[s], ob));
            best[s]  = min(best[s], ob);
        }
    }
    if (col == 0) {
#pragma unroll
        for (int rt = 0; rt < 4; ++rt)
#pragma unroll
            for (int r = 0; r < 4; ++r) {
                const int pl = w * 64 + rt * 16 + quad * 4 + r;   // C/D row map
                bu1[pl] = best[rt * 4 + r];
                bu2[pl] = best2[rt * 4 + r];
            }
    }
    __syncthreads();

    pb1[half * NPIX + n0 + t] = bu1[t];
    pb2[half * NPIX + n0 + t] = bu2[t];
}

// Merge halves + epilogue: indices, worklist, o, loss.
__global__ __launch_bounds__(256) void vq_post(
    const float* __restrict__ x, const float* __restrict__ emb,
    const unsigned* __restrict__ pb1, const unsigned* __restrict__ pb2,
    float* __restrict__ o, float* __restrict__ idx_out,
    float* __restrict__ acc, unsigned* __restrict__ wl_count,
    unsigned* __restrict__ wl, unsigned cap)
{
    __shared__ float wred[4];
    const int t = threadIdx.x;
    const int lane = t & 63, w = t >> 6;
    const int n = blockIdx.x * 256 + t;
    const int b = n >> 12, p = n & 4095;

    const unsigned b0 = pb1[n], b1 = pb1[NPIX + n];
    const unsigned s0 = pb2[n], s1 = pb2[NPIX + n];
    const unsigned bu  = min(b0, b1);
    const unsigned bu2 = min(min(s0, s1), max(b0, b1));
    const unsigned bidx = bu & 1023u;
    idx_out[n] = (float)bidx;
    const unsigned qg = (bu2 >> 10) - (bu >> 10);
    if (qg < MARGIN_Q) {
        unsigned pos = atomicAdd(wl_count, 1u);
        if (pos < cap) wl[pos] = (unsigned)n;
    }

    float ss = 0.f;
    {
        const float4* er4 = (const float4*)(emb + (size_t)bidx * CCH);
        const float* xbt = x + (size_t)b * (CCH * HW) + p;
        float* ob = o + (size_t)b * (CCH * HW) + p;
#pragma unroll
        for (int i = 0; i < 16; ++i) {
            float4 ev = er4[i];
            float evv[4] = {ev.x, ev.y, ev.z, ev.w};
#pragma unroll
            for (int q = 0; q < 4; ++q) {
                const int c = i * 4 + q;
                float xv = xbt[(size_t)c * HW];
                float e  = evv[q];
                ob[(size_t)c * HW] = xv + (e - xv);
                float d = xv - e;
                ss = fmaf(d, d, ss);
            }
        }
    }
    for (int off = 32; off; off >>= 1) ss += __shfl_down(ss, off, 64);
    if (lane == 0) wred[w] = ss;
    __syncthreads();
    if (t == 0) atomicAdd(acc, (wred[0] + wred[1]) + (wred[2] + wred[3]));
}

// Exact fp64 refine: one BLOCK per ambiguous pixel, 4 codes per thread.
__global__ __launch_bounds__(256) void vq_refine(
    const float* __restrict__ x, const float* __restrict__ emb,
    float* __restrict__ o, float* __restrict__ idx_out,
    float* __restrict__ acc, const unsigned* __restrict__ wl_count,
    const unsigned* __restrict__ wl, unsigned cap)
{
    __shared__ float zsh[CCH];
    __shared__ double rbd[4];
    __shared__ int rbi[4];
    __shared__ int s_pk;
    unsigned cnt = *wl_count; if (cnt > cap) cnt = cap;
    const int t = threadIdx.x;

    for (unsigned i = blockIdx.x; i < cnt; i += gridDim.x) {
        const int n = (int)wl[i];
        const int b = n >> 12, p = n & 4095;
        if (t < CCH) zsh[t] = x[(size_t)b * (CCH * HW) + (size_t)t * HW + p];
        __syncthreads();

        double bd = 1e300; int bi = KCODES;
        for (int j = 0; j < 4; ++j) {
            const int k = t + j * 256;
            const float* er = emb + (size_t)k * CCH;
            double d0 = 0.0, d1 = 0.0, d2 = 0.0, d3 = 0.0;   // ILP-4
#pragma unroll
            for (int c = 0; c < CCH; c += 4) {
                double t0 = (double)zsh[c + 0] - (double)er[c + 0];
                double t1 = (double)zsh[c + 1] - (double)er[c + 1];
                double t2 = (double)zsh[c + 2] - (double)er[c + 2];
                double t3 = (double)zsh[c + 3] - (double)er[c + 3];
                d0 = fma(t0, t0, d0); d1 = fma(t1, t1, d1);
                d2 = fma(t2, t2, d2); d3 = fma(t3, t3, d3);
            }
            double d = (d0 + d1) + (d2 + d3);
            if (d < bd) { bd = d; bi = k; }
        }
        for (int dlt = 1; dlt < 64; dlt <<= 1) {
            double od = __shfl_xor(bd, dlt, 64);
            int    oi = __shfl_xor(bi, dlt, 64);
            if (od < bd || (od == bd && oi < bi)) { bd = od; bi = oi; }
        }
        const int wv = t >> 6;
        if ((t & 63) == 0) { rbd[wv] = bd; rbi[wv] = bi; }
        __syncthreads();
        if (t == 0) {
            double fb = rbd[0]; int fi = rbi[0];
            for (int q = 1; q < 4; ++q)
                if (rbd[q] < fb || (rbd[q] == fb && rbi[q] < fi)) { fb = rbd[q]; fi = rbi[q]; }
            const int old = (int)idx_out[n];
            if (fi != old) { idx_out[n] = (float)fi; s_pk = (old << 16) | fi; }
            else s_pk = -1;
        }
        __syncthreads();
        const int pk = s_pk;
        if (pk >= 0 && t < CCH) {
            const int old = pk >> 16, fi = pk & 0xFFFF;
            const float xv = zsh[t];
            const float eo = emb[(size_t)old * CCH + t];
            const float en = emb[(size_t)fi  * CCH + t];
            o[(size_t)b * (CCH * HW) + (size_t)t * HW + p] = xv + (en - xv);
            const float dn = xv - en, dd = xv - eo;
            float delta = dn * dn - dd * dd;
            for (int off = 32; off; off >>= 1) delta += __shfl_down(delta, off, 64);
            if (t == 0) atomicAdd(acc, delta);
        }
        __syncthreads();
    }
}

__global__ void vq_fin(const float* __restrict__ acc, float* __restrict__ loss) {
    *loss = 1.25f * (*acc) * (1.0f / (float)NELEM);
}

extern "C" void kernel_launch(void* const* d_in, const int* in_sizes, int n_in,
                              void* d_out, int out_size, void* d_ws, size_t ws_size,
                              hipStream_t stream) {
    const float* x   = (const float*)d_in[0];
    const float* emb = (const float*)d_in[1];
    float*    out = (float*)d_out;
    float*    wsf = (float*)d_ws;
    unsigned* wsu = (unsigned*)d_ws;
    char*     wsb = (char*)d_ws;

    float* o_out    = out;
    float* loss_out = out + NELEM;
    float* idx_out  = out + NELEM + 1;
    float* eeb_g    = wsf + WS_EEB_F;
    f16*   cbH      = (f16*)(wsb + WS_CBH_B);
    f16*   cbL      = (f16*)(wsb + WS_CBL_B);
    unsigned* pb1   = wsu + WS_PB1_U;
    unsigned* pb2   = wsu + WS_PB2_U;
    unsigned* wl    = wsu + WS_WL_U;
    unsigned cap = 0;
    if (ws_size / 4 > WS_WL_U) {
        size_t c = ws_size / 4 - WS_WL_U;
        cap = (unsigned)(c > NPIX ? NPIX : c);
    }

    vq_prep<<<33, 256, 0, stream>>>(emb, wsf, wsu, cbH, cbL, eeb_g);
    vq_main<<<(NPIX / MB) * KSPLIT, 256, 0, stream>>>(x, cbH, cbL, eeb_g, pb1, pb2);
    vq_post<<<NPIX / 256, 256, 0, stream>>>(x, emb, pb1, pb2, o_out, idx_out,
                                            wsf, wsu + 1, wl, cap);
    vq_refine<<<1024, 256, 0, stream>>>(x, emb, o_out, idx_out, wsf,
                                        wsu + 1, wl, cap);
    vq_fin<<<1, 1, 0, stream>>>(wsf, loss_out);
}

// Round 7
// 188.114 us; speedup vs baseline: 1.6754x; 1.6754x over previous
//
#include <hip/hip_runtime.h>

// VQ-VAE quantization. x: [32,64,64,64] fp32, emb: [1024,64] fp32
#define BATCH   32
#define CCH     64
#define HW      4096
#define NPIX    131072
#define KCODES  1024
#define NELEM   (NPIX * CCH)        // 8388608
#define KSPLIT  4                   // codebook quarters across blocks
#define CPB     256                 // codes per block (resident in LDS)
#define PPB     1024                // pixels per block
#define MARGIN_Q 2u                 // ambiguity margin, 1/2048 units

typedef _Float16 f16;
typedef __attribute__((ext_vector_type(8))) _Float16 f16x8;
typedef __attribute__((ext_vector_type(4))) _Float16 f16x4;
typedef __attribute__((ext_vector_type(4))) float    f32x4;

static __device__ __forceinline__ f32x4 mfma16(f16x8 a, f16x8 b, f32x4 c) {
    return __builtin_amdgcn_mfma_f32_16x16x32_f16(a, b, c, 0, 0, 0);
}

// ws layout: [0] f32 loss acc, [1] u32 done counter,
// pb1 (u32, best, 4 halves x NPIX) at u32 1024, pbg (u8 gap, 4 x NPIX) after.
#define WS_PB1_U   1024
#define WS_PBG_B   (4096 + 4 * NPIX * 4)

__global__ __launch_bounds__(512, 2) void vq_main(
    const float* __restrict__ x, const float* __restrict__ emb,
    unsigned* __restrict__ pb1, unsigned char* __restrict__ pbg,
    float* __restrict__ wsf, unsigned* __restrict__ wsu)
{
    __shared__ __align__(16) f16 cbH[CPB * CCH];   // 32 KB, swizzled
    __shared__ __align__(16) f16 cbL[CPB * CCH];   // 32 KB
    __shared__ float eebl[CPB];                    // 1 KB

    const int t    = threadIdx.x;
    const int lane = t & 63;
    const int w    = t >> 6;               // wave 0..7
    const int col  = lane & 15;
    const int quad = lane >> 4;
    const int c7   = col & 7;
    const int sw0  = 8 * (quad ^ c7);      // swizzled granule, chans 0..31
    const int sw1  = sw0 ^ 32;             // chans 32..63
    const int gb   = blockIdx.x & 127;     // pixel group
    const int half = blockIdx.x >> 7;      // codebook quarter 0..3
    const int n0   = gb * PPB;
    const int b    = n0 >> 12;
    const int p0   = n0 & 4095;
    const int kbase = half * CPB;
    const float* xb = x + (size_t)b * (CCH * HW) + p0;
    const float* cb = emb + (size_t)kbase * CCH;

    if (blockIdx.x == 0 && t == 0) { wsf[0] = 0.f; wsu[1] = 0u; }

    // ---- phase A: quarter codebook -> LDS, split fp16 hi/lo, swizzled ----
    {
        const float4* src = (const float4*)cb;     // 4096 float4
#pragma unroll
        for (int i = 0; i < 8; ++i) {
            const int j = i * 512 + t;
            float4 v = src[j];
            const int code = j >> 4, ch4 = j & 15;
            f16x4 h = {(f16)v.x, (f16)v.y, (f16)v.z, (f16)v.w};
            f16x4 l = {(f16)(v.x - (float)h[0]), (f16)(v.y - (float)h[1]),
                       (f16)(v.z - (float)h[2]), (f16)(v.w - (float)h[3])};
            const int off = code * 64 + 8 * ((ch4 >> 1) ^ (code & 7)) + (ch4 & 1) * 4;
            *(f16x4*)&cbH[off] = h;
            *(f16x4*)&cbL[off] = l;
        }
        if (t < CPB) {
            const float4* row4 = (const float4*)(cb + (size_t)t * CCH);
            float s = 0.f;
#pragma unroll
            for (int i = 0; i < 16; ++i) {
                float4 v = row4[i];
                s = fmaf(v.x, v.x, s); s = fmaf(v.y, v.y, s);
                s = fmaf(v.z, v.z, s); s = fmaf(v.w, v.w, s);
            }
            eebl[t] = fmaf(s, 2048.0f, 1048576.0f);
        }
    }
    __syncthreads();       // the ONLY barrier — codebook stays resident

    // ---- pixel loop: 2 iters x (8 waves x 64 px), no barriers ----
    for (int it = 0; it < PPB / 512; ++it) {
        // A fragments from global (MFMA A-layout), fp16 split
        f16x8 aH[4][2], aL[4][2];
#pragma unroll
        for (int rt = 0; rt < 4; ++rt) {
            const int pp = it * 512 + w * 64 + rt * 16 + col;
#pragma unroll
            for (int kc = 0; kc < 2; ++kc) {
                f16x8 h, l;
#pragma unroll
                for (int j = 0; j < 8; ++j) {
                    const int c = kc * 32 + quad * 8 + j;
                    float zs = -2.0f * xb[(size_t)c * HW + pp];
                    f16 hh = (f16)zs;
                    h[j] = hh;
                    l[j] = (f16)(zs - (float)hh);
                }
                aH[rt][kc] = h;
                aL[rt][kc] = l;
            }
        }

        unsigned best[16], best2[16];
#pragma unroll
        for (int s = 0; s < 16; ++s) { best[s] = 0xFFFFFFFFu; best2[s] = 0xFFFFFFFFu; }

#pragma unroll 4
        for (int tile = 0; tile < CPB / 16; ++tile) {
            const int row = tile * 16 + col;
            const f16* bh = cbH + row * 64;
            const f16* bl = cbL + row * 64;
            f16x8 bH0 = *(const f16x8*)(bh + sw0);
            f16x8 bH1 = *(const f16x8*)(bh + sw1);
            f16x8 bL0 = *(const f16x8*)(bl + sw0);
            f16x8 bL1 = *(const f16x8*)(bl + sw1);
            const float eebc = eebl[row];
            const unsigned kb = (unsigned)(kbase + row);
#pragma unroll
            for (int rt = 0; rt < 4; ++rt) {
                f32x4 a4 = {0.f, 0.f, 0.f, 0.f};
                a4 = mfma16(aH[rt][0], bH0, a4);
                a4 = mfma16(aH[rt][1], bH1, a4);
                a4 = mfma16(aL[rt][0], bH0, a4);
                a4 = mfma16(aL[rt][1], bH1, a4);
                a4 = mfma16(aH[rt][0], bL0, a4);
                a4 = mfma16(aH[rt][1], bL1, a4);
#pragma unroll
                for (int r = 0; r < 4; ++r) {
                    float uf = fmaf(a4[r], 2048.0f, eebc);   // in (0, 2^21)
                    unsigned pk = (((unsigned)uf) << 10) | kb;
                    const int s = rt * 4 + r;
                    best2[s] = min(best2[s], max(pk, best[s]));
                    best[s]  = min(best[s], pk);
                }
            }
        }

        // cross-lane argmin over the 16 code-columns (lane bits 0..3)
#pragma unroll
        for (int d = 1; d < 16; d <<= 1) {
#pragma unroll
            for (int s = 0; s < 16; ++s) {
                unsigned ob  = __shfl_xor(best[s],  d, 64);
                unsigned ob2 = __shfl_xor(best2[s], d, 64);
                best2[s] = min(min(best2[s], ob2), max(best[s], ob));
                best[s]  = min(best[s], ob);
            }
        }
        if (col == 0) {
            const unsigned baseN = (unsigned)(half * NPIX + n0 + it * 512 + w * 64);
#pragma unroll
            for (int rt = 0; rt < 4; ++rt)
#pragma unroll
                for (int r = 0; r < 4; ++r) {
                    const unsigned idx = baseN + rt * 16 + quad * 4 + r;  // C/D row map
                    const unsigned bb = best[rt * 4 + r];
                    unsigned qg = (best2[rt * 4 + r] >> 10) - (bb >> 10);
                    pb1[idx] = bb;
                    pbg[idx] = (unsigned char)min(qg, 255u);
                }
        }
    }
}

// Merge quarters + epilogue + inline exact refine + fused loss finalize.
__global__ __launch_bounds__(256) void vq_post(
    const float* __restrict__ x, const float* __restrict__ emb,
    const unsigned* __restrict__ pb1, const unsigned char* __restrict__ pbg,
    float* __restrict__ o, float* __restrict__ idx_out,
    float* __restrict__ loss_out, float* __restrict__ acc,
    unsigned* __restrict__ done)
{
    __shared__ float wred[4];
    __shared__ unsigned amb[256];
    __shared__ unsigned ambn;
    __shared__ float zsh[CCH];
    __shared__ double rbd[4];
    __shared__ int rbi[4];
    __shared__ int s_pk;
    __shared__ float s_extra;

    const int t = threadIdx.x, lane = t & 63, w = t >> 6;
    const int n = blockIdx.x * 256 + t;
    const int b = n >> 12, p = n & 4095;
    if (t == 0) { ambn = 0u; s_extra = 0.f; }
    __syncthreads();

    // exact 4-way merge of (best, gap)
    const unsigned b0 = pb1[n], b1 = pb1[NPIX + n];
    const unsigned b2 = pb1[2 * NPIX + n], b3 = pb1[3 * NPIX + n];
    const unsigned m1 = min(b0, b1), M1 = max(b0, b1);
    const unsigned m2 = min(b2, b3), M2 = max(b2, b3);
    const unsigned bu = min(m1, m2);
    const unsigned sb = min(max(m1, m2), min(M1, M2));   // 2nd-smallest best
    const unsigned gsel = (bu == b0) ? pbg[n] : (bu == b1) ? pbg[NPIX + n]
                        : (bu == b2) ? pbg[2 * NPIX + n] : pbg[3 * NPIX + n];
    const unsigned bidx = bu & 1023u;
    idx_out[n] = (float)bidx;
    const unsigned qb = bu >> 10;
    const unsigned qsec = min(sb >> 10, qb + gsel);
    if (qsec - qb < MARGIN_Q) { unsigned pos = atomicAdd(&ambn, 1u); amb[pos] = (unsigned)t; }

    // epilogue: o and loss partial
    float ss = 0.f;
    {
        const float4* er4 = (const float4*)(emb + (size_t)bidx * CCH);
        const float* xbt = x + (size_t)b * (CCH * HW) + p;
        float* ob = o + (size_t)b * (CCH * HW) + p;
#pragma unroll
        for (int i = 0; i < 16; ++i) {
            float4 ev = er4[i];
            float evv[4] = {ev.x, ev.y, ev.z, ev.w};
#pragma unroll
            for (int q = 0; q < 4; ++q) {
                const int c = i * 4 + q;
                float xv = xbt[(size_t)c * HW];
                float e  = evv[q];
                ob[(size_t)c * HW] = xv + (e - xv);
                float d = xv - e;
                ss = fmaf(d, d, ss);
            }
        }
    }
    for (int off = 32; off; off >>= 1) ss += __shfl_down(ss, off, 64);
    if (lane == 0) wred[w] = ss;
    __syncthreads();

    // inline exact fp64 refine of this block's ambiguous pixels (usually none)
    unsigned cnt = ambn; if (cnt > 256u) cnt = 256u;
    for (unsigned u2 = 0; u2 < cnt; ++u2) {
        const int nn = blockIdx.x * 256 + (int)amb[u2];
        const int bb2 = nn >> 12, pp2 = nn & 4095;
        if (t < CCH) zsh[t] = x[(size_t)bb2 * (CCH * HW) + (size_t)t * HW + pp2];
        __syncthreads();

        double bd = 1e300; int bi = KCODES;
        for (int j = 0; j < 4; ++j) {
            const int k = t + j * 256;
            const float* er = emb + (size_t)k * CCH;
            double d0 = 0.0, d1 = 0.0, d2 = 0.0, d3 = 0.0;
#pragma unroll
            for (int c = 0; c < CCH; c += 4) {
                double t0 = (double)zsh[c + 0] - (double)er[c + 0];
                double t1 = (double)zsh[c + 1] - (double)er[c + 1];
                double t2 = (double)zsh[c + 2] - (double)er[c + 2];
                double t3 = (double)zsh[c + 3] - (double)er[c + 3];
                d0 = fma(t0, t0, d0); d1 = fma(t1, t1, d1);
                d2 = fma(t2, t2, d2); d3 = fma(t3, t3, d3);
            }
            double d = (d0 + d1) + (d2 + d3);
            if (d < bd) { bd = d; bi = k; }
        }
        for (int dlt = 1; dlt < 64; dlt <<= 1) {
            double od = __shfl_xor(bd, dlt, 64);
            int    oi = __shfl_xor(bi, dlt, 64);
            if (od < bd || (od == bd && oi < bi)) { bd = od; bi = oi; }
        }
        if (lane == 0) { rbd[w] = bd; rbi[w] = bi; }
        __syncthreads();
        if (t == 0) {
            double fb = rbd[0]; int fi = rbi[0];
            for (int q = 1; q < 4; ++q)
                if (rbd[q] < fb || (rbd[q] == fb && rbi[q] < fi)) { fb = rbd[q]; fi = rbi[q]; }
            const int old = (int)idx_out[nn];
            if (fi != old) { idx_out[nn] = (float)fi; s_pk = (old << 16) | fi; }
            else s_pk = -1;
        }
        __syncthreads();
        const int pk = s_pk;
        if (t < 64) {                       // wave 0, all 64 lanes active
            float delta = 0.f;
            if (pk >= 0) {
                const int old = pk >> 16, fi = pk & 0xFFFF;
                const float xv = zsh[t];
                const float eo = emb[(size_t)old * CCH + t];
                const float en = emb[(size_t)fi  * CCH + t];
                o[(size_t)bb2 * (CCH * HW) + (size_t)t * HW + pp2] = xv + (en - xv);
                const float dn = xv - en, dd = xv - eo;
                delta = dn * dn - dd * dd;
            }
            for (int off = 32; off; off >>= 1) delta += __shfl_down(delta, off, 64);
            if (t == 0) s_extra += delta;
        }
        __syncthreads();
    }

    // fused loss finalize: last block to finish writes the scalar
    if (t == 0) {
        float tot = (wred[0] + wred[1]) + (wred[2] + wred[3]) + s_extra;
        atomicAdd(acc, tot);
        __threadfence();
        unsigned old = atomicAdd(done, 1u);
        if (old == gridDim.x - 1) {
            __threadfence();
            float fin = atomicAdd(acc, 0.f);     // atomic read of final sum
            loss_out[0] = 1.25f * fin * (1.0f / (float)NELEM);
        }
    }
}

extern "C" void kernel_launch(void* const* d_in, const int* in_sizes, int n_in,
                              void* d_out, int out_size, void* d_ws, size_t ws_size,
                              hipStream_t stream) {
    const float* x   = (const float*)d_in[0];
    const float* emb = (const float*)d_in[1];
    float*    out = (float*)d_out;
    float*    wsf = (float*)d_ws;
    unsigned* wsu = (unsigned*)d_ws;
    char*     wsb = (char*)d_ws;

    float* o_out    = out;                 // [32,64,64,64]
    float* loss_out = out + NELEM;         // scalar
    float* idx_out  = out + NELEM + 1;     // [32,64,64]
    unsigned*      pb1 = wsu + WS_PB1_U;
    unsigned char* pbg = (unsigned char*)(wsb + WS_PBG_B);

    vq_main<<<(NPIX / PPB) * KSPLIT, 512, 0, stream>>>(x, emb, pb1, pbg, wsf, wsu);
    vq_post<<<NPIX / 256, 256, 0, stream>>>(x, emb, pb1, pbg, o_out, idx_out,
                                            loss_out, wsf, wsu + 1);
}

// Round 8
// 177.808 us; speedup vs baseline: 1.7725x; 1.0580x over previous
//
#include <hip/hip_runtime.h>

// VQ-VAE quantization, single fused kernel.
// x: [32,64,64,64] fp32, emb: [1024,64] fp32
#define CCH     64
#define HW      4096
#define NPIX    131072
#define KCODES  1024
#define NELEM   (NPIX * CCH)        // 8388608
#define PPB     512                 // pixels per block (grid 256 = 1 block/CU)
#define HALFK   512                 // codes resident per pass
#define MARGIN_Q 2u                 // ambiguity margin, 1/2048 distance units

typedef _Float16 f16;
typedef __attribute__((ext_vector_type(8))) _Float16 f16x8;
typedef __attribute__((ext_vector_type(4))) float    f32x4;

static __device__ __forceinline__ f32x4 mfma16(f16x8 a, f16x8 b, f32x4 c) {
    return __builtin_amdgcn_mfma_f32_16x16x32_f16(a, b, c, 0, 0, 0);
}
static __device__ __forceinline__ unsigned med3u(unsigned a, unsigned b, unsigned c) {
    unsigned d;
    asm("v_med3_u32 %0, %1, %2, %3" : "=v"(d) : "v"(a), "v"(b), "v"(c));
    return d;
}

__global__ __launch_bounds__(512, 2) void vq_fused(
    const float* __restrict__ x, const float* __restrict__ emb,
    float* __restrict__ o, float* __restrict__ idx_out,
    float* __restrict__ partial)
{
    __shared__ __align__(16) f16 cbH[HALFK * CCH];   // 64 KB
    __shared__ __align__(16) f16 cbL[HALFK * CCH];   // 64 KB
    __shared__ float eebl[HALFK];                    // 2 KB
    __shared__ unsigned buS[PPB];                    // 2 KB
    __shared__ float wred[8];

    const int t    = threadIdx.x;
    const int lane = t & 63;
    const int w    = t >> 6;               // wave 0..7
    const int col  = lane & 15;
    const int quad = lane >> 4;
    const int sw0  = 8 * (quad ^ (col & 7));   // swizzled granule, chans 0..31
    const int sw1  = sw0 ^ 32;                 // chans 32..63
    const int n0   = blockIdx.x * PPB;
    const int b    = n0 >> 12;
    const int p0   = n0 & 4095;
    const float* xb = x + (size_t)b * (CCH * HW) + p0;

    // ---- A fragments straight from global (MFMA A-layout), fp16 hi/lo split ----
    f16x8 aH[4][2], aL[4][2];
#pragma unroll
    for (int rt = 0; rt < 4; ++rt) {
        const int pp = w * 64 + rt * 16 + col;
#pragma unroll
        for (int kc = 0; kc < 2; ++kc) {
            f16x8 h, l;
#pragma unroll
            for (int j = 0; j < 8; ++j) {
                const int c = kc * 32 + quad * 8 + j;
                float zs = -2.0f * xb[(size_t)c * HW + pp];
                f16 hh = (f16)zs;
                h[j] = hh;
                l[j] = (f16)(zs - (float)hh);
            }
            aH[rt][kc] = h;
            aL[rt][kc] = l;
        }
    }

    unsigned best[16], best2[16];
#pragma unroll
    for (int s = 0; s < 16; ++s) { best[s] = 0xFFFFFFFFu; best2[s] = 0xFFFFFFFFu; }

    // ---- two passes over the codebook, half resident in LDS each ----
    for (int half = 0; half < 2; ++half) {
        const int kbase = half * HALFK;
        {   // fill: thread t converts code row (kbase+t), fp16 split + swizzle + ee
            const float* src = emb + (size_t)(kbase + t) * CCH;
            float s = 0.f;
#pragma unroll
            for (int g = 0; g < 8; ++g) {
                float4 v0 = *(const float4*)(src + g * 8);
                float4 v1 = *(const float4*)(src + g * 8 + 4);
                float vv[8] = {v0.x, v0.y, v0.z, v0.w, v1.x, v1.y, v1.z, v1.w};
                f16x8 h, l;
#pragma unroll
                for (int j = 0; j < 8; ++j) {
                    f16 hh = (f16)vv[j];
                    h[j] = hh;
                    l[j] = (f16)(vv[j] - (float)hh);
                    s = fmaf(vv[j], vv[j], s);
                }
                const int off = t * 64 + 8 * (g ^ (t & 7));
                *(f16x8*)&cbH[off] = h;
                *(f16x8*)&cbL[off] = l;
            }
            eebl[t] = fmaf(s, 2048.0f, 1048576.0f);   // 2048*ee + 2^20
        }
        __syncthreads();    // fill visible

#pragma unroll 4
        for (int tile = 0; tile < HALFK / 16; ++tile) {
            const int row = tile * 16 + col;
            const f16* bh = cbH + row * 64;
            const f16* bl = cbL + row * 64;
            f16x8 bH0 = *(const f16x8*)(bh + sw0);
            f16x8 bH1 = *(const f16x8*)(bh + sw1);
            f16x8 bL0 = *(const f16x8*)(bl + sw0);
            f16x8 bL1 = *(const f16x8*)(bl + sw1);
            const float eebc = eebl[row];
            const unsigned kb = (unsigned)(kbase + row);
#pragma unroll
            for (int rt = 0; rt < 4; ++rt) {
                f32x4 a4 = {0.f, 0.f, 0.f, 0.f};
                a4 = mfma16(aH[rt][0], bH0, a4);
                a4 = mfma16(aH[rt][1], bH1, a4);
                a4 = mfma16(aL[rt][0], bH0, a4);
                a4 = mfma16(aL[rt][1], bH1, a4);
                a4 = mfma16(aH[rt][0], bL0, a4);
                a4 = mfma16(aH[rt][1], bL1, a4);
#pragma unroll
                for (int r = 0; r < 4; ++r) {
                    float uf = fmaf(a4[r], 2048.0f, eebc);    // in (0, 2^21)
                    unsigned pk = (((unsigned)uf) << 10) | kb;
                    const int s = rt * 4 + r;
                    best2[s] = med3u(pk, best[s], best2[s]);  // second-min update
                    best[s]  = min(best[s], pk);
                }
            }
        }
        __syncthreads();    // scan done before next fill overwrites
    }

    // ---- cross-lane argmin reduce over the 16 code-columns ----
#pragma unroll
    for (int d = 1; d < 16; d <<= 1) {
#pragma unroll
        for (int s = 0; s < 16; ++s) {
            unsigned ob  = __shfl_xor(best[s],  d, 64);
            unsigned ob2 = __shfl_xor(best2[s], d, 64);
            best2[s] = med3u(best[s], ob, min(best2[s], ob2));
            best[s]  = min(best[s], ob);
        }
    }
    if (col == 0) {
#pragma unroll
        for (int rt = 0; rt < 4; ++rt)
#pragma unroll
            for (int r = 0; r < 4; ++r) {
                const int s = rt * 4 + r;
                const unsigned bb = best[s];
                const unsigned fl =
                    (((best2[s] >> 10) - (bb >> 10)) < MARGIN_Q) ? 0x80000000u : 0u;
                buS[w * 64 + rt * 16 + quad * 4 + r] = bb | fl;   // C/D row map
            }
    }
    __syncthreads();

    // ---- epilogue: one pixel per thread ----
    const unsigned bu = buS[t];
    const unsigned bidx = bu & 1023u;
    idx_out[n0 + t] = (float)bidx;
    float ss = 0.f;
    {
        const float4* er4 = (const float4*)(emb + (size_t)bidx * CCH);
        const float* xbt = xb + t;
        float* ob = o + (size_t)b * (CCH * HW) + p0 + t;
#pragma unroll
        for (int i = 0; i < 16; ++i) {
            float4 ev = er4[i];
            float evv[4] = {ev.x, ev.y, ev.z, ev.w};
#pragma unroll
            for (int q = 0; q < 4; ++q) {
                const int c = i * 4 + q;
                float xv = xbt[(size_t)c * HW];
                float e  = evv[q];
                ob[(size_t)c * HW] = xv + (e - xv);
                float d = xv - e;
                ss = fmaf(d, d, ss);
            }
        }
    }
    for (int off = 32; off; off >>= 1) ss += __shfl_down(ss, off, 64);
    // lane0 now holds this wave's loss partial in ss

    // ---- per-wave exact fp64 refine of flagged pixels (rare) ----
    unsigned long long flags = __ballot((bu >> 31) != 0u);
    float extra = 0.f;
    while (flags) {
        const int m = __ffsll((long long)flags) - 1;
        flags &= flags - 1;
        const int pp2 = p0 + w * 64 + m;
        const int n   = n0 + w * 64 + m;
        // broadcast pixel's channel vector: lane c loads x[b][c][pp2]
        const float zval = x[(size_t)b * (CCH * HW) + (size_t)lane * HW + pp2];
        float zf[CCH];
#pragma unroll
        for (int c = 0; c < CCH; ++c) zf[c] = __shfl(zval, c, 64);

        double bd = 1e300; int bi = 0;
        for (int j = 0; j < 16; ++j) {
            const int k = lane * 16 + j;                  // ascending in-lane
            const float4* er4 = (const float4*)(emb + (size_t)k * CCH);
            double d0 = 0.0, d1 = 0.0;
#pragma unroll
            for (int i = 0; i < 16; ++i) {
                float4 ev = er4[i];
                double t0 = (double)zf[i * 4 + 0] - (double)ev.x;
                double t1 = (double)zf[i * 4 + 1] - (double)ev.y;
                double t2 = (double)zf[i * 4 + 2] - (double)ev.z;
                double t3 = (double)zf[i * 4 + 3] - (double)ev.w;
                d0 = fma(t0, t0, d0); d1 = fma(t1, t1, d1);
                d0 = fma(t2, t2, d0); d1 = fma(t3, t3, d1);
            }
            double d = d0 + d1;
            if (d < bd) { bd = d; bi = k; }
        }
        for (int dlt = 1; dlt < 64; dlt <<= 1) {
            double od = __shfl_xor(bd, dlt, 64);
            int    oi = __shfl_xor(bi, dlt, 64);
            if (od < bd || (od == bd && oi < bi)) { bd = od; bi = oi; }
        }
        const int oldi = (int)(buS[w * 64 + m] & 1023u);
        if (bi != oldi) {
            if (lane == 0) idx_out[n] = (float)bi;
            const float xv = zval;                        // lane == channel
            const float eo = emb[(size_t)oldi * CCH + lane];
            const float en = emb[(size_t)bi   * CCH + lane];
            o[(size_t)b * (CCH * HW) + (size_t)lane * HW + pp2] = xv + (en - xv);
            const float dn = xv - en, dd = xv - eo;
            float delta = dn * dn - dd * dd;
            for (int off = 32; off; off >>= 1) delta += __shfl_down(delta, off, 64);
            extra += delta;                               // only lane0's matters
        }
    }

    if (lane == 0) wred[w] = ss + extra;
    __syncthreads();
    if (t == 0) {
        float tot = 0.f;
#pragma unroll
        for (int i = 0; i < 8; ++i) tot += wred[i];
        partial[blockIdx.x] = tot;                        // plain store, no init needed
    }
}

__global__ void vq_fin(const float* __restrict__ partial, float* __restrict__ loss) {
    __shared__ float r[4];
    const int t = threadIdx.x, lane = t & 63, w = t >> 6;
    float s = partial[t];
    for (int off = 32; off; off >>= 1) s += __shfl_down(s, off, 64);
    if (lane == 0) r[w] = s;
    __syncthreads();
    if (t == 0) loss[0] = 1.25f * ((r[0] + r[1]) + (r[2] + r[3])) * (1.0f / (float)NELEM);
}

extern "C" void kernel_launch(void* const* d_in, const int* in_sizes, int n_in,
                              void* d_out, int out_size, void* d_ws, size_t ws_size,
                              hipStream_t stream) {
    const float* x   = (const float*)d_in[0];
    const float* emb = (const float*)d_in[1];
    float* out = (float*)d_out;
    float* wsf = (float*)d_ws;

    float* o_out    = out;                 // [32,64,64,64]
    float* loss_out = out + NELEM;         // scalar
    float* idx_out  = out + NELEM + 1;     // [32,64,64]

    vq_fused<<<NPIX / PPB, PPB, 0, stream>>>(x, emb, o_out, idx_out, wsf);
    vq_fin<<<1, 256, 0, stream>>>(wsf, loss_out);
}